// Round 1
// baseline (3815.458 us; speedup 1.0000x reference)
//
#include <hip/hip_runtime.h>

// Problem constants (from reference)
constexpr int kNGene = 40000;
constexpr int kNGoid = 10000;
constexpr int kN     = 50000;
constexpr int kE     = 800000;
constexpr int kInDim = 1280;
constexpr int kH1    = 256;
constexpr int kH2    = 128;
constexpr int kOut   = 64;
constexpr int kGDim  = 4096;
constexpr int kD1    = 1024;

// ---------------- degree / norm ----------------
__global__ void k_deg_init(float* deg) {
  int i = blockIdx.x * blockDim.x + threadIdx.x;
  if (i < kN) deg[i] = 1.0f;  // self-loop
}
__global__ void k_deg_count(const int* __restrict__ ei, float* __restrict__ deg) {
  int e = blockIdx.x * blockDim.x + threadIdx.x;
  if (e < kE) atomicAdd(&deg[ei[kE + e]], 1.0f);
}
__global__ void k_rsqrt(float* deg) {
  int i = blockIdx.x * blockDim.x + threadIdx.x;
  if (i < kN) deg[i] = rsqrtf(deg[i]);  // deg >= 1 always
}

// ---------------- fp32 tiled GEMM: C[M,N] = A[M,K] @ B[K,N] (+bias)(+relu) ----
// A row-major with stride lda (lets us slice x[:40000,:1280] out of 4096-wide x)
// B row-major K x N, ldb = N. All K % 16 == 0, all N % 64 == 0 in this problem.
__global__ __launch_bounds__(256)
void k_gemm_f32(const float* __restrict__ A, int lda,
                const float* __restrict__ B, int ldb,
                const float* __restrict__ bias,
                float* __restrict__ C, int ldc,
                int M, int Ncol, int K, int do_relu)
{
  __shared__ float As[16][65];  // A tile transposed: As[k][row]
  __shared__ float Bs[16][68];  // pad 68 keeps float4 LDS stores 16B-aligned
  const int tid = threadIdx.x;
  const int tx = tid & 15, ty = tid >> 4;
  const int row0 = blockIdx.y * 64;
  const int col0 = blockIdx.x * 64;
  float acc[4][4] = {};
  for (int k0 = 0; k0 < K; k0 += 16) {
    {
      int r = tid >> 2;          // 0..63
      int c = (tid & 3) << 2;    // 0,4,8,12
      int grow = row0 + r;
      float4 v = make_float4(0.f, 0.f, 0.f, 0.f);
      if (grow < M)
        v = *reinterpret_cast<const float4*>(A + (size_t)grow * lda + k0 + c);
      As[c + 0][r] = v.x; As[c + 1][r] = v.y; As[c + 2][r] = v.z; As[c + 3][r] = v.w;
    }
    {
      int r = tid >> 4;          // 0..15
      int c = (tid & 15) << 2;   // 0..60
      int gcol = col0 + c;
      float4 v = make_float4(0.f, 0.f, 0.f, 0.f);
      if (gcol < Ncol)
        v = *reinterpret_cast<const float4*>(B + (size_t)(k0 + r) * ldb + gcol);
      *reinterpret_cast<float4*>(&Bs[r][c]) = v;
    }
    __syncthreads();
#pragma unroll
    for (int k = 0; k < 16; ++k) {
      float a[4], b[4];
#pragma unroll
      for (int i = 0; i < 4; ++i) a[i] = As[k][ty + 16 * i];
#pragma unroll
      for (int j = 0; j < 4; ++j) b[j] = Bs[k][tx + 16 * j];
#pragma unroll
      for (int i = 0; i < 4; ++i)
#pragma unroll
        for (int j = 0; j < 4; ++j)
          acc[i][j] = fmaf(a[i], b[j], acc[i][j]);
    }
    __syncthreads();
  }
#pragma unroll
  for (int i = 0; i < 4; ++i) {
    int r = row0 + ty + 16 * i;
    if (r >= M) continue;
#pragma unroll
    for (int j = 0; j < 4; ++j) {
      int ccol = col0 + tx + 16 * j;
      if (ccol >= Ncol) continue;
      float v = acc[i][j];
      if (bias) v += bias[ccol];
      if (do_relu) v = fmaxf(v, 0.f);
      C[(size_t)r * ldc + ccol] = v;
    }
  }
}

// ---------------- GCN aggregation (only dst < kNGene rows are ever used) ----
template <int F>
__global__ void k_self_loop(const float* __restrict__ xw, const float* __restrict__ dinv,
                            float* __restrict__ agg) {
  int idx = blockIdx.x * blockDim.x + threadIdx.x;
  if (idx >= kNGene * F) return;
  int i = idx / F;
  float d = dinv[i];
  agg[idx] = xw[idx] * d * d;
}

template <int F>
__global__ void k_scatter(const int* __restrict__ ei, const float* __restrict__ dinv,
                          const float* __restrict__ xw, float* __restrict__ agg) {
  int e = blockIdx.x;
  int dst = ei[kE + e];
  if (dst >= kNGene) return;  // aggregation into GOID rows is overwritten later
  int src = ei[e];
  float norm = dinv[src] * dinv[dst];
  int f = threadIdx.x;
  atomicAdd(&agg[(size_t)dst * F + f], xw[(size_t)src * F + f] * norm);
}

template <int F>
__global__ void k_finalize(float* __restrict__ h, const float* __restrict__ bias) {
  int idx = blockIdx.x * blockDim.x + threadIdx.x;
  if (idx >= kNGene * F) return;
  h[idx] = fmaxf(h[idx] + bias[idx & (F - 1)], 0.f);
}

__global__ void k_copy(float* __restrict__ dstp, const float* __restrict__ srcp, int n) {
  int i = blockIdx.x * blockDim.x + threadIdx.x;
  if (i < n) dstp[i] = srcp[i];
}

extern "C" void kernel_launch(void* const* d_in, const int* in_sizes, int n_in,
                              void* d_out, int out_size, void* d_ws, size_t ws_size,
                              hipStream_t stream) {
  const float* x   = (const float*)d_in[0];
  const int*   ei  = (const int*)d_in[1];
  // d_in[2] = mask (unused)
  const float* Wd1 = (const float*)d_in[3];
  const float* bd1 = (const float*)d_in[4];
  const float* Wd2 = (const float*)d_in[5];
  const float* bd2 = (const float*)d_in[6];
  const float* W1  = (const float*)d_in[7];
  const float* b1  = (const float*)d_in[8];
  const float* W2  = (const float*)d_in[9];
  const float* b2  = (const float*)d_in[10];
  const float* Wp1 = (const float*)d_in[11];
  const float* bp1 = (const float*)d_in[12];
  const float* Wp2 = (const float*)d_in[13];
  const float* bp2 = (const float*)d_in[14];
  const float* Wf  = (const float*)d_in[15];
  const float* bf  = (const float*)d_in[16];
  float* out = (float*)d_out;
  float* ws  = (float*)d_ws;

  // workspace layout (floats); peak = 51,250,000 floats = 205 MB
  float* goid_t = ws;                  // 12,800,000  (10000 x 1280)
  float* h1tmp  = ws + 12800000;       // 10,240,000  (10000 x 1024) -> reused as xw2
  float* xw1    = ws + 23040000;       // 12,800,000  (50000 x 256)  -> reused as h2
  float* h1     = ws + 35840000;       // 12,800,000  (50000 x 256)
  float* p1     = ws + 48640000;       //  2,560,000  (10000 x 256)
  float* dinv   = ws + 51200000;       //     50,000
  float* xw2 = h1tmp;                  // (50000 x 128) = 6.4M <= 10.24M  OK
  float* h2  = xw1;                    // (50000 x 128) = 6.4M <= 12.8M   OK

  const float* gene_x = x;                               // rows 0..39999, cols 0..1279, lda=4096
  const float* goid_x = x + (size_t)kNGene * kGDim;      // rows 40000..49999, full 4096

  auto g = [](int M, int Ncol) { return dim3((unsigned)((Ncol + 63) / 64), (unsigned)((M + 63) / 64)); };

  // 1) symmetric-norm degrees
  k_deg_init<<<(kN + 255) / 256, 256, 0, stream>>>(dinv);
  k_deg_count<<<(kE + 255) / 256, 256, 0, stream>>>(ei, dinv);
  k_rsqrt<<<(kN + 255) / 256, 256, 0, stream>>>(dinv);

  // 2) GOID MLP: goid_t = relu(relu(goid_x@Wd1+bd1)@Wd2+bd2)
  k_gemm_f32<<<g(kNGoid, kD1), 256, 0, stream>>>(goid_x, kGDim, Wd1, kD1, bd1, h1tmp, kD1,
                                                 kNGoid, kD1, kGDim, 1);
  k_gemm_f32<<<g(kNGoid, kInDim), 256, 0, stream>>>(h1tmp, kD1, Wd2, kInDim, bd2, goid_t, kInDim,
                                                    kNGoid, kInDim, kD1, 1);

  // 3) xw1 = x_t @ W1 (gene slice + goid_t), no bias (bias applied post-agg)
  k_gemm_f32<<<g(kNGene, kH1), 256, 0, stream>>>(gene_x, kGDim, W1, kH1, nullptr, xw1, kH1,
                                                 kNGene, kH1, kInDim, 0);
  k_gemm_f32<<<g(kNGoid, kH1), 256, 0, stream>>>(goid_t, kInDim, W1, kH1, nullptr,
                                                 xw1 + (size_t)kNGene * kH1, kH1,
                                                 kNGoid, kH1, kInDim, 0);

  // 4) p1 = goid_t @ Wp1 + bp1
  k_gemm_f32<<<g(kNGoid, kH1), 256, 0, stream>>>(goid_t, kInDim, Wp1, kH1, bp1, p1, kH1,
                                                 kNGoid, kH1, kInDim, 0);

  // 5) conv1 aggregation -> h1 (gene rows), goid rows = p1
  k_self_loop<kH1><<<(kNGene * kH1 + 255) / 256, 256, 0, stream>>>(xw1, dinv, h1);
  k_scatter<kH1><<<kE, kH1, 0, stream>>>(ei, dinv, xw1, h1);
  k_finalize<kH1><<<(kNGene * kH1 + 255) / 256, 256, 0, stream>>>(h1, b1);
  k_copy<<<(kNGoid * kH1 + 255) / 256, 256, 0, stream>>>(h1 + (size_t)kNGene * kH1, p1, kNGoid * kH1);

  // 6) xw2 = h1 @ W2 (all 50000 rows; goid rows feed messages)
  k_gemm_f32<<<g(kN, kH2), 256, 0, stream>>>(h1, kH1, W2, kH2, nullptr, xw2, kH2,
                                             kN, kH2, kH1, 0);

  // 7) conv2 aggregation -> h2 (gene rows); goid rows = p1@Wp2+bp2
  k_self_loop<kH2><<<(kNGene * kH2 + 255) / 256, 256, 0, stream>>>(xw2, dinv, h2);
  k_scatter<kH2><<<kE, kH2, 0, stream>>>(ei, dinv, xw2, h2);
  k_finalize<kH2><<<(kNGene * kH2 + 255) / 256, 256, 0, stream>>>(h2, b2);
  k_gemm_f32<<<g(kNGoid, kH2), 256, 0, stream>>>(p1, kH1, Wp2, kH2, bp2,
                                                 h2 + (size_t)kNGene * kH2, kH2,
                                                 kNGoid, kH2, kH1, 0);

  // 8) out = h2 @ Wf + bf
  k_gemm_f32<<<g(kN, kOut), 256, 0, stream>>>(h2, kH2, Wf, kOut, bf, out, kOut,
                                              kN, kOut, kH2, 0);
}